// Round 3
// baseline (102.482 us; speedup 1.0000x reference)
//
#include <hip/hip_runtime.h>
#include <hip/hip_bf16.h>
#include <math.h>

#define B_   4
#define T1_  4096
#define T2_  512
#define IC_  32
#define OC_  64
#define KS_  64

typedef unsigned short u16;
typedef unsigned int   u32;
typedef __attribute__((ext_vector_type(8))) short  short8;   // 8 bf16 = 4 VGPRs
typedef __attribute__((ext_vector_type(4))) float  float4v;  // MFMA C/D frag

__device__ __forceinline__ float bf2f(u16 h) {
    union { u32 u; float f; } v; v.u = ((u32)h) << 16; return v.f;
}
__device__ __forceinline__ u16 f2bf(float f) {
    union { u32 u; float f; } v; v.f = f;
    u32 u = v.u;
    u32 r = (u + 0x7FFFu + ((u >> 16) & 1u)) >> 16;   // round-to-nearest-even
    return (u16)r;
}

#define PI_F 3.14159265358979323846f

// ---------------------------------------------------------------------------
// prep: kernel (o,c,s) fp32 -> Bsz bf16 in MFMA B-fragment order.
// cs = c*64+s (contraction index). B[k=cs][n=o].
// B-frag for 16x16x32: lane(n + 16*q) holds B[kb*32 + q*8 + j][n], j=0..7.
// Bsz flat index = (cs>>3)*512 + o*8 + (cs&7)  -> frag load is 16B contiguous.
// ---------------------------------------------------------------------------
__global__ __launch_bounds__(256) void prep_kernel(const float* __restrict__ kern,
                                                   u16* __restrict__ Bsz)
{
    int gid = blockIdx.x * 256 + threadIdx.x;   // 0..16383
    int o   = gid & 63;                          // lane-contiguous -> coalesced writes
    int cs8 = gid >> 6;                          // 0..255
    const float* p = kern + (size_t)o * 2048 + cs8 * 8;
    float4 a = *(const float4*)p;
    float4 b = *(const float4*)(p + 4);
    u16* q = Bsz + (size_t)cs8 * 512 + o * 8;
    *(ushort4*)(q)     = make_ushort4(f2bf(a.x), f2bf(a.y), f2bf(a.z), f2bf(a.w));
    *(ushort4*)(q + 4) = make_ushort4(f2bf(b.x), f2bf(b.y), f2bf(b.z), f2bf(b.w));
}

// ---------------------------------------------------------------------------
// interp: per (b,t2) block. Fractional-delay filter w[64] (closed form of
// irfft(rfft(kernel)*shift), incl. Nyquist cos term) applied circularly to the
// 64x32 x-window; writes Y[bt][cs=c*64+s] bf16 (A-matrix for the MFMA gemm).
// ---------------------------------------------------------------------------
__global__ __launch_bounds__(256) void interp_kernel(const float* __restrict__ x,
                                                     const float* __restrict__ index,
                                                     u16* __restrict__ Y)
{
    __shared__ __align__(16) float xwT[IC_][68];   // [c][k], pad 68 for banks
    __shared__ __align__(16) float wsh[64];

    const int bt  = blockIdx.x;
    const int b   = bt >> 9;        // T2_ = 512
    const int tid = threadIdx.x;

    float fidx = index[bt];
    float flo  = floorf(fidx);
    int   i0   = (int)flo;
    float f    = fidx - flo;

    // ---- load x window (zero-padded) into LDS, transposed to [c][k] ----
    {
        int e  = tid * 8;          // flat over (k,c): e = k*32 + c0
        int k  = e >> 5;           // 0..63
        int c0 = e & 31;           // multiple of 8
        int pos = i0 + k - 32;     // position in x time axis
        float vals[8];
        if (pos >= 0 && pos < T1_) {
            const float* p = x + ((size_t)(b * T1_ + pos) * IC_ + c0);
            float4 a = *(const float4*)p;
            float4 d = *(const float4*)(p + 4);
            vals[0]=a.x; vals[1]=a.y; vals[2]=a.z; vals[3]=a.w;
            vals[4]=d.x; vals[5]=d.y; vals[6]=d.z; vals[7]=d.w;
        } else {
            #pragma unroll
            for (int q = 0; q < 8; ++q) vals[q] = 0.0f;
        }
        #pragma unroll
        for (int q = 0; q < 8; ++q) xwT[c0 + q][k] = vals[q];
    }

    // ---- w[j] = D(j+f), D(u) = sin(pi u) cos(pi u/64) / (64 sin(pi u/64)) ----
    if (tid < 64) {
        int j = tid;
        float wj;
        if (f <= 0.0f) {
            wj = (j == 0) ? 1.0f : 0.0f;
        } else {
            float spf = sinf(PI_F * f);          // sin(pi(j+f)) = (-1)^j sin(pi f)
            float a   = PI_F * ((float)j + f) * (1.0f / 64.0f);
            float sa  = sinf(a);
            float ca  = cosf(a);
            wj = ((j & 1) ? -spf : spf) * ca / (64.0f * sa);
        }
        wsh[j] = wj;
    }
    __syncthreads();

    // ---- thread owns (c, s0..s0+7); rotated register window ----
    const int c  = tid >> 3;           // 0..31
    const int s0 = (tid & 7) << 3;     // 0..56 step 8

    float xr[64];
    #pragma unroll
    for (int q = 0; q < 16; ++q) {
        int idx = (s0 + q * 4) & 63;   // 4-aligned, wraps at 64
        const float4 v = *(const float4*)&xwT[c][idx];
        xr[q*4+0] = v.x; xr[q*4+1] = v.y; xr[q*4+2] = v.z; xr[q*4+3] = v.w;
    }

    float acc[8];
    #pragma unroll
    for (int r = 0; r < 8; ++r) acc[r] = 0.0f;

    // w via float4 LDS reads (16 b128 instead of 64 b32 on the LDS pipe)
    #pragma unroll
    for (int jq = 0; jq < 16; ++jq) {
        const float4 wv = *(const float4*)&wsh[jq * 4];
        #pragma unroll
        for (int jj = 0; jj < 4; ++jj) {
            const float wj = (jj == 0) ? wv.x : (jj == 1) ? wv.y : (jj == 2) ? wv.z : wv.w;
            const int j = jq * 4 + jj;
            #pragma unroll
            for (int r = 0; r < 8; ++r)
                acc[r] += wj * xr[(j + r) & 63];   // static index after unroll
        }
    }

    // ---- write Y[bt][c*64 + s0..s0+7] bf16 (16B per thread, coalesced) ----
    u16 ov[8];
    #pragma unroll
    for (int r = 0; r < 8; ++r) ov[r] = f2bf(acc[r]);
    u16* yp = Y + ((size_t)bt * 2048 + c * 64 + s0);
    *(ushort4*)(yp)     = make_ushort4(ov[0], ov[1], ov[2], ov[3]);
    *(ushort4*)(yp + 4) = make_ushort4(ov[4], ov[5], ov[6], ov[7]);
}

// ---------------------------------------------------------------------------
// gemm (MFMA): out[M=2048 bt][N=64 o] = Y[2048x2048] @ B[2048x64] + bias.
// One wave per block, Mtile=16, full K. 64 K-steps x 4 n-tiles = 256 MFMA.
// A-frag: lane(m + 16q) reads Y[bt0+m][kb*32 + q*8 .. +7]       (16B global)
// B-frag: lane(n + 16q) reads Bsz[(kb*4+q)*512 + (nt*16+n)*8]   (16B global)
// C/D   : lane L, reg r -> row (L>>4)*4+r (bt), col L&15 (o in tile)
// ---------------------------------------------------------------------------
__global__ __launch_bounds__(64) void gemm_kernel(const u16* __restrict__ Y,
                                                  const u16* __restrict__ Bsz,
                                                  const float* __restrict__ bias,
                                                  float* __restrict__ out)
{
    const int lane = threadIdx.x;      // 0..63
    const int nm   = lane & 15;        // m for A-frag, n for B-frag, col for D
    const int q    = lane >> 4;        // quad
    const int bt0  = blockIdx.x * 16;

    float4v acc0 = {0.f, 0.f, 0.f, 0.f};
    float4v acc1 = {0.f, 0.f, 0.f, 0.f};
    float4v acc2 = {0.f, 0.f, 0.f, 0.f};
    float4v acc3 = {0.f, 0.f, 0.f, 0.f};

    const u16* aptr = Y   + (size_t)(bt0 + nm) * 2048 + q * 8;
    const u16* bptr = Bsz + (size_t)q * 512 + nm * 8;

    short8 a  = *(const short8*)(aptr);
    short8 b0 = *(const short8*)(bptr);
    short8 b1 = *(const short8*)(bptr + 128);
    short8 b2 = *(const short8*)(bptr + 256);
    short8 b3 = *(const short8*)(bptr + 384);

    for (int kb = 0; kb < 64; ++kb) {
        short8 an, bn0, bn1, bn2, bn3;
        if (kb != 63) {
            const u16* ap = aptr + (kb + 1) * 32;
            const u16* bp = bptr + (size_t)(kb + 1) * 2048;
            an  = *(const short8*)(ap);
            bn0 = *(const short8*)(bp);
            bn1 = *(const short8*)(bp + 128);
            bn2 = *(const short8*)(bp + 256);
            bn3 = *(const short8*)(bp + 384);
        }
        acc0 = __builtin_amdgcn_mfma_f32_16x16x32_bf16(a, b0, acc0, 0, 0, 0);
        acc1 = __builtin_amdgcn_mfma_f32_16x16x32_bf16(a, b1, acc1, 0, 0, 0);
        acc2 = __builtin_amdgcn_mfma_f32_16x16x32_bf16(a, b2, acc2, 0, 0, 0);
        acc3 = __builtin_amdgcn_mfma_f32_16x16x32_bf16(a, b3, acc3, 0, 0, 0);
        if (kb != 63) { a = an; b0 = bn0; b1 = bn1; b2 = bn2; b3 = bn3; }
    }

    // ---- epilogue: + bias, fp32 store ----
    const float bs0 = bias[nm];
    const float bs1 = bias[16 + nm];
    const float bs2 = bias[32 + nm];
    const float bs3 = bias[48 + nm];
    #pragma unroll
    for (int r = 0; r < 4; ++r) {
        const int row = bt0 + q * 4 + r;
        float* op = out + (size_t)row * 64 + nm;
        op[0]  = acc0[r] + bs0;
        op[16] = acc1[r] + bs1;
        op[32] = acc2[r] + bs2;
        op[48] = acc3[r] + bs3;
    }
}

// ---------------------------------------------------------------------------
extern "C" void kernel_launch(void* const* d_in, const int* in_sizes, int n_in,
                              void* d_out, int out_size, void* d_ws, size_t ws_size,
                              hipStream_t stream)
{
    const float* x     = (const float*)d_in[0];   // (4,4096,32) fp32
    const float* index = (const float*)d_in[1];   // (4,512) fp32
    const float* kern  = (const float*)d_in[2];   // (64,32,64) fp32
    const float* bias  = (const float*)d_in[3];   // (64,) fp32
    float* out = (float*)d_out;                   // (4,512,64) fp32

    u16* Y   = (u16*)d_ws;                                      // 2048*2048 bf16 = 8 MB
    u16* Bsz = (u16*)((char*)d_ws + (size_t)8 * 1024 * 1024);   // 256 KB

    prep_kernel<<<dim3(64),  dim3(256), 0, stream>>>(kern, Bsz);
    interp_kernel<<<dim3(B_ * T2_), dim3(256), 0, stream>>>(x, index, Y);
    gemm_kernel<<<dim3(B_ * T2_ / 16), dim3(64), 0, stream>>>(Y, Bsz, bias, out);
}

// Round 4
// 79.390 us; speedup vs baseline: 1.2909x; 1.2909x over previous
//
#include <hip/hip_runtime.h>
#include <hip/hip_bf16.h>
#include <math.h>

#define B_   4
#define T1_  4096
#define T2_  512
#define IC_  32
#define OC_  64
#define KS_  64

typedef unsigned short u16;
typedef unsigned int   u32;
typedef __attribute__((ext_vector_type(8))) short  short8;   // 8 bf16 = 4 VGPRs
typedef __attribute__((ext_vector_type(4))) float  float4v;  // MFMA C/D frag

__device__ __forceinline__ float bf2f(u16 h) {
    union { u32 u; float f; } v; v.u = ((u32)h) << 16; return v.f;
}
__device__ __forceinline__ u16 f2bf(float f) {
    union { u32 u; float f; } v; v.f = f;
    u32 u = v.u;
    u32 r = (u + 0x7FFFu + ((u >> 16) & 1u)) >> 16;   // round-to-nearest-even
    return (u16)r;
}

#define PI_F 3.14159265358979323846f

// ---------------------------------------------------------------------------
// K1: fused prep + interp.
//   blocks [0,64):   prep — kernel (o,c,s) fp32 -> Bsz bf16 in MFMA B-frag
//                    order: Bsz[(cs>>3)*512 + o*8 + (cs&7)], cs = c*64+s.
//   blocks [64,1088): interp — 2 bt rows per block. Fractional-delay filter
//                    w[64] (closed form of irfft(rfft(k)*shift), incl Nyquist
//                    cos term) circularly applied to the 64x32 x-window.
//                    Y[bt][cs=c*64+s] bf16 (A-matrix for MFMA gemm).
// ---------------------------------------------------------------------------
__global__ __launch_bounds__(256) void prep_interp_kernel(
        const float* __restrict__ x, const float* __restrict__ index,
        const float* __restrict__ kern, u16* __restrict__ Y,
        u16* __restrict__ Bsz)
{
    __shared__ __align__(16) float xwT[2][IC_][68];  // [half][c][k], pad 68
    __shared__ __align__(16) float wsh[2][64];

    const int tid = threadIdx.x;

    if (blockIdx.x < 64) {                  // ---- prep branch ----
        int gid = blockIdx.x * 256 + tid;   // 0..16383
        int o   = gid & 63;
        int cs8 = gid >> 6;                 // 0..255
        const float* p = kern + (size_t)o * 2048 + cs8 * 8;
        float4 a = *(const float4*)p;
        float4 b = *(const float4*)(p + 4);
        u16* q = Bsz + (size_t)cs8 * 512 + o * 8;
        *(ushort4*)(q)     = make_ushort4(f2bf(a.x), f2bf(a.y), f2bf(a.z), f2bf(a.w));
        *(ushort4*)(q + 4) = make_ushort4(f2bf(b.x), f2bf(b.y), f2bf(b.z), f2bf(b.w));
        return;
    }

    // ---- interp branch: this block handles bt = 2*p2 and 2*p2+1 ----
    const int p2 = blockIdx.x - 64;

    #pragma unroll
    for (int h = 0; h < 2; ++h) {
        const int bt = p2 * 2 + h;
        const int b  = bt >> 9;             // T2_ = 512
        float fidx = index[bt];
        float flo  = floorf(fidx);
        int   i0   = (int)flo;
        float f    = fidx - flo;

        // load 64x32 window (zero-padded) transposed into LDS [c][k]
        int e  = tid * 8;                   // e = k*32 + c0
        int k  = e >> 5;                    // 0..63
        int c0 = e & 31;
        int pos = i0 + k - 32;
        float vals[8];
        if (pos >= 0 && pos < T1_) {
            const float* p = x + ((size_t)(b * T1_ + pos) * IC_ + c0);
            float4 a = *(const float4*)p;
            float4 d = *(const float4*)(p + 4);
            vals[0]=a.x; vals[1]=a.y; vals[2]=a.z; vals[3]=a.w;
            vals[4]=d.x; vals[5]=d.y; vals[6]=d.z; vals[7]=d.w;
        } else {
            #pragma unroll
            for (int q = 0; q < 8; ++q) vals[q] = 0.0f;
        }
        #pragma unroll
        for (int q = 0; q < 8; ++q) xwT[h][c0 + q][k] = vals[q];

        // w[j] = D(j+f), D(u) = sin(pi u) cos(pi u/64) / (64 sin(pi u/64))
        if (tid < 64) {
            int j = tid;
            float wj;
            if (f <= 0.0f) {
                wj = (j == 0) ? 1.0f : 0.0f;
            } else {
                float spf = sinf(PI_F * f);     // sin(pi(j+f)) = (-1)^j sin(pi f)
                float a   = PI_F * ((float)j + f) * (1.0f / 64.0f);
                wj = ((j & 1) ? -spf : spf) * cosf(a) / (64.0f * sinf(a));
            }
            wsh[h][j] = wj;
        }
    }
    __syncthreads();

    // thread owns (h, c, s0..s0+15): 2*32*4 = 256 threads
    const int h   = tid >> 7;
    const int rem = tid & 127;
    const int c   = rem >> 2;               // 0..31
    const int s0  = (rem & 3) << 4;         // 0,16,32,48

    // rotated register window: xr[i] = xw[(s0+i)&63]
    float xr[64];
    #pragma unroll
    for (int q = 0; q < 16; ++q) {
        int idx = (s0 + q * 4) & 63;        // 4-aligned, no wrap inside float4
        const float4 v = *(const float4*)&xwT[h][c][idx];
        xr[q*4+0] = v.x; xr[q*4+1] = v.y; xr[q*4+2] = v.z; xr[q*4+3] = v.w;
    }

    float acc[16];
    #pragma unroll
    for (int r = 0; r < 16; ++r) acc[r] = 0.0f;

    #pragma unroll
    for (int jq = 0; jq < 16; ++jq) {
        const float4 wv = *(const float4*)&wsh[h][jq * 4];  // wave-uniform
        #pragma unroll
        for (int jj = 0; jj < 4; ++jj) {
            const float wj = (jj == 0) ? wv.x : (jj == 1) ? wv.y : (jj == 2) ? wv.z : wv.w;
            const int j = jq * 4 + jj;
            #pragma unroll
            for (int r = 0; r < 16; ++r)
                acc[r] += wj * xr[(j + r) & 63];   // static reg index after unroll
        }
    }

    // store Y[bt][c*64 + s0 .. +15] bf16 (32 B per thread, coalesced)
    const int bt = p2 * 2 + h;
    union { u16 u[8]; short8 v; } o0, o1;
    #pragma unroll
    for (int r = 0; r < 8; ++r) { o0.u[r] = f2bf(acc[r]); o1.u[r] = f2bf(acc[8 + r]); }
    u16* yp = Y + ((size_t)bt * 2048 + c * 64 + s0);
    *(short8*)(yp)     = o0.v;
    *(short8*)(yp + 8) = o1.v;
}

// ---------------------------------------------------------------------------
// K2 (MFMA gemm): out[M=2048 bt][N=64 o] = Y @ B + bias.
// 128 blocks x 256 threads (4 waves). Wave w covers K-range [w*512,(w+1)*512)
// = 16 kb-iters of 16x16x32; 4 n-tiles. LDS cross-wave reduction + bias.
// A-frag: lane(m+16q) reads Y[bt0+m][kb*32+q*8 ..+7]        (16B global)
// B-frag: lane(n+16q) reads Bsz[(kb*4+q)*512 + (nt*16+n)*8] (16B global)
// C/D   : lane L, reg r -> row (L>>4)*4+r (bt), col L&15 (o within n-tile)
// ---------------------------------------------------------------------------
__global__ __launch_bounds__(256) void gemm_kernel(const u16* __restrict__ Y,
                                                   const u16* __restrict__ Bsz,
                                                   const float* __restrict__ bias,
                                                   float* __restrict__ out)
{
    __shared__ float red[4][4][16][17];    // [wave][ntile][row][col], pad 17

    const int tid  = threadIdx.x;
    const int w    = tid >> 6;             // 0..3
    const int lane = tid & 63;
    const int nm   = lane & 15;
    const int q    = lane >> 4;
    const int bt0  = blockIdx.x * 16;
    const int kb0  = w * 16;

    const u16* aptr = Y   + (size_t)(bt0 + nm) * 2048 + kb0 * 32 + q * 8;
    const u16* bptr = Bsz + (size_t)kb0 * 2048 + q * 512 + nm * 8;

    float4v acc0 = {0.f,0.f,0.f,0.f};
    float4v acc1 = {0.f,0.f,0.f,0.f};
    float4v acc2 = {0.f,0.f,0.f,0.f};
    float4v acc3 = {0.f,0.f,0.f,0.f};

    short8 a  = *(const short8*)(aptr);
    short8 b0 = *(const short8*)(bptr);
    short8 b1 = *(const short8*)(bptr + 128);
    short8 b2 = *(const short8*)(bptr + 256);
    short8 b3 = *(const short8*)(bptr + 384);

    for (int kb = 0; kb < 16; ++kb) {
        short8 an, bn0, bn1, bn2, bn3;
        if (kb != 15) {
            const u16* ap = aptr + (kb + 1) * 32;
            const u16* bp = bptr + (size_t)(kb + 1) * 2048;
            an  = *(const short8*)(ap);
            bn0 = *(const short8*)(bp);
            bn1 = *(const short8*)(bp + 128);
            bn2 = *(const short8*)(bp + 256);
            bn3 = *(const short8*)(bp + 384);
        }
        acc0 = __builtin_amdgcn_mfma_f32_16x16x32_bf16(a, b0, acc0, 0, 0, 0);
        acc1 = __builtin_amdgcn_mfma_f32_16x16x32_bf16(a, b1, acc1, 0, 0, 0);
        acc2 = __builtin_amdgcn_mfma_f32_16x16x32_bf16(a, b2, acc2, 0, 0, 0);
        acc3 = __builtin_amdgcn_mfma_f32_16x16x32_bf16(a, b3, acc3, 0, 0, 0);
        if (kb != 15) { a = an; b0 = bn0; b1 = bn1; b2 = bn2; b3 = bn3; }
    }

    #pragma unroll
    for (int r = 0; r < 4; ++r) {
        red[w][0][q * 4 + r][nm] = acc0[r];
        red[w][1][q * 4 + r][nm] = acc1[r];
        red[w][2][q * 4 + r][nm] = acc2[r];
        red[w][3][q * 4 + r][nm] = acc3[r];
    }
    __syncthreads();

    #pragma unroll
    for (int e = tid; e < 1024; e += 256) {
        int row = e >> 6, oc = e & 63, nt = oc >> 4, col = oc & 15;
        float s = red[0][nt][row][col] + red[1][nt][row][col]
                + red[2][nt][row][col] + red[3][nt][row][col] + bias[oc];
        out[(size_t)(bt0 + row) * 64 + oc] = s;
    }
}

// ---------------------------------------------------------------------------
extern "C" void kernel_launch(void* const* d_in, const int* in_sizes, int n_in,
                              void* d_out, int out_size, void* d_ws, size_t ws_size,
                              hipStream_t stream)
{
    const float* x     = (const float*)d_in[0];   // (4,4096,32) fp32
    const float* index = (const float*)d_in[1];   // (4,512) fp32
    const float* kern  = (const float*)d_in[2];   // (64,32,64) fp32
    const float* bias  = (const float*)d_in[3];   // (64,) fp32
    float* out = (float*)d_out;                   // (4,512,64) fp32

    u16* Y   = (u16*)d_ws;                                      // 2048*2048 bf16 = 8 MB
    u16* Bsz = (u16*)((char*)d_ws + (size_t)8 * 1024 * 1024);   // 256 KB

    prep_interp_kernel<<<dim3(64 + B_ * T2_ / 2), dim3(256), 0, stream>>>(x, index, kern, Y, Bsz);
    gemm_kernel<<<dim3(B_ * T2_ / 16), dim3(256), 0, stream>>>(Y, Bsz, bias, out);
}